// Round 6
// baseline (139.891 us; speedup 1.0000x reference)
//
#include <hip/hip_runtime.h>
#include <math.h>

// Problem constants (baked from reference setup_inputs):
// B=2, N=1024, Din=64, D=64, K=24
#define BB 2
#define NN 1024
#define DD 64
#define KK 24
#define NPTS (BB * NN)  // 2048

#if __has_builtin(__builtin_amdgcn_exp2f)
#define EXP2(x) __builtin_amdgcn_exp2f(x)
#else
#define EXP2(x) exp2f(x)
#endif

typedef float v2f __attribute__((ext_vector_type(2)));

// Force VOP3P packed f32 math (LLVM does not form these from ext_vector ops).
static __device__ __forceinline__ v2f pk_fma(v2f a, v2f b, v2f c) {
    v2f d;
    asm("v_pk_fma_f32 %0, %1, %2, %3" : "=v"(d) : "v"(a), "v"(b), "v"(c));
    return d;
}
static __device__ __forceinline__ v2f pk_add(v2f a, v2f b) {
    v2f d;
    asm("v_pk_add_f32 %0, %1, %2" : "=v"(d) : "v"(a), "v"(b));
    return d;
}

// ---------------------------------------------------------------------------
// Workspace layout (bytes):
//   feat : [2048][64] float   @ 0        (512 KiB)
//   idx  : [2048][24] int     @ 524288   (192 KiB)
//   rwP  : [4096] float4      @ 720896   (64 KiB)  {rw0,rw1,rw2,rb}*log2(e)
// ---------------------------------------------------------------------------

// Fused prep + MLP + KNN, role-split by blockIdx:
//   blocks [0,512)    : MLP, 4 points per block
//   blocks [512,528)  : rw/rb prescale+interleave
//   blocks [528,1040) : KNN, 4 points per block (one wave per point)
__global__ __launch_bounds__(256) void prep_mlp_knn_kernel(
    const float* __restrict__ feature, const float* __restrict__ xyz,
    const float* __restrict__ pw1, const float* __restrict__ pb1,
    const float* __restrict__ pw2, const float* __restrict__ pb2,
    const float* __restrict__ rw, const float* __restrict__ rb,
    float* __restrict__ feat, int* __restrict__ idx_out,
    float4* __restrict__ rwP) {
    int bid = blockIdx.x;
    int tid = threadIdx.x;

    if (bid < 512) {
        // ---- MLP: feat = relu(relu(feature@pw1+pb1)@pw2+pb2), 4 rows/block
        int r = tid >> 6;
        int d = tid & 63;
        int row = bid * 4 + r;
        __shared__ float s_in[4][64];
        __shared__ float s_h[4][64];
        s_in[r][d] = feature[row * 64 + d];
        __syncthreads();
        float h = pb1[d];
#pragma unroll
        for (int i = 0; i < 64; i++) h = __builtin_fmaf(s_in[r][i], pw1[i * 64 + d], h);
        h = fmaxf(h, 0.f);
        s_h[r][d] = h;
        __syncthreads();
        float f = pb2[d];
#pragma unroll
        for (int i = 0; i < 64; i++) f = __builtin_fmaf(s_h[r][i], pw2[i * 64 + d], f);
        f = fmaxf(f, 0.f);
        feat[row * 64 + d] = f;
    } else if (bid < 528) {
        // ---- prescale rw/rb by log2(e), interleave to float4 per column
        const float LOG2E = 1.4426950408889634f;
        int t = (bid - 512) * 256 + tid;  // 0..4095
        float4 v;
        v.x = rw[t] * LOG2E;
        v.y = rw[4096 + t] * LOG2E;
        v.z = rw[8192 + t] * LOG2E;
        v.w = rb[t] * LOG2E;
        rwP[t] = v;
    } else {
        // ---- KNN: one wave per point, iterative argmin (24 rounds)
        int w = tid >> 6;
        int lane = tid & 63;
        int pt = (bid - 528) * 4 + w;
        int b = pt >> 10;
        int n = pt & 1023;
        const float* xb = xyz + (size_t)b * NN * 3;
        float xn = xb[n * 3 + 0], yn = xb[n * 3 + 1], zn = xb[n * 3 + 2];
        float sqn = xn * xn + yn * yn + zn * zn;
        float dist[16];
#pragma unroll
        for (int c = 0; c < 16; c++) {
            int m = c * 64 + lane;
            float xm = xb[m * 3 + 0], ym = xb[m * 3 + 1], zm = xb[m * 3 + 2];
            float sqm = xm * xm + ym * ym + zm * zm;
            float dot = xn * xm + yn * ym + zn * zm;
            dist[c] = sqn + sqm - 2.0f * dot;
        }
        for (int r = 0; r < KK; r++) {
            float best = 3.4e38f;
            int bi = 1 << 30;
#pragma unroll
            for (int c = 0; c < 16; c++) {
                if (dist[c] < best) {  // strict < keeps lowest index on ties
                    best = dist[c];
                    bi = c * 64 + lane;
                }
            }
#pragma unroll
            for (int off = 32; off >= 1; off >>= 1) {
                float ob = __shfl_down(best, off);
                int oi = __shfl_down(bi, off);
                if (ob < best || (ob == best && oi < bi)) {
                    best = ob;
                    bi = oi;
                }
            }
            bi = __shfl(bi, 0);
            if ((bi & 63) == lane) dist[bi >> 6] = 3.4e38f;
            if (lane == 0) idx_out[pt * KK + r] = bi;
        }
    }
}

// Fused weight-gen + softmax (over K*D, per column d) + aggregate + final
// linear. One block (4 waves) per point; lane = d; wave w owns j in
// [w*16, w*16+16). Hot loop: v_pk_fma_f32 + v_exp_f32.
// rel (rx/ry/rz, 36 v2f = 72 VGPRs, loop-invariant) is PINNED in VGPRs via
// empty asm: without it the compiler's pressure-reduction sinks these LDS
// loads back into the hot loop (R5: VGPR_Count stayed 64 even with a raised
// cap, ~18 extra ds_reads/jj, measured-busy matched the sunk model).
#define GVS 28  // s_gvt row stride (112B: 16B-aligned float4 reads, 8-way write conflict only)
__global__ __launch_bounds__(256, 2) void agg_kernel(const float* __restrict__ xyz,
                                                     const float* __restrict__ feat,
                                                     const int* __restrict__ idx,
                                                     const float4* __restrict__ rwP,
                                                     const float* __restrict__ sw,
                                                     const float* __restrict__ sb,
                                                     float* __restrict__ out) {
    int pt = blockIdx.x;
    int b = pt >> 10;
    int n = pt & 1023;
    int tid = threadIdx.x;
    int w = tid >> 6;
    int d = tid & 63;

    __shared__ __align__(8) float s_relT[3][28];    // [c][k], padded
    __shared__ __align__(16) float s_gvt[64][GVS];  // [j][k]
    __shared__ float s_red[8][64];
    __shared__ float s_pre[64];

    const float* xb = xyz + (size_t)b * NN * 3;
    if (tid < KK * 3) {
        int k = tid % KK, c = tid / KK;
        int nb = idx[pt * KK + k];
        s_relT[c][k] = xb[nb * 3 + c] - xb[n * 3 + c];
    }
    for (int t = tid; t < KK * 64; t += 256) {
        int k = t >> 6, j = t & 63;
        int nb = idx[pt * KK + k];
        s_gvt[j][k] = feat[((size_t)b * NN + nb) * 64 + j];
    }
    __syncthreads();

    // rel pairs in registers (contiguous v2f loads from transposed layout)
    v2f rx[12], ry[12], rz[12];
#pragma unroll
    for (int k = 0; k < 12; k++) {
        rx[k] = *(const v2f*)&s_relT[0][2 * k];
        ry[k] = *(const v2f*)&s_relT[1][2 * k];
        rz[k] = *(const v2f*)&s_relT[2][2 * k];
    }
    // PIN: opaque def per value — the sinking/remat pass cannot push these
    // back to per-use LDS reads inside the hot loop.
#pragma unroll
    for (int k = 0; k < 12; k++) {
        asm volatile("" : "+v"(rx[k]), "+v"(ry[k]), "+v"(rz[k]));
    }

    v2f l0 = {0.f, 0.f}, l1 = {0.f, 0.f}, a0 = {0.f, 0.f}, a1 = {0.f, 0.f};
    int col0 = (w * 16) * 64 + d;
    float4 rv = rwP[col0];
    for (int jj = 0; jj < 16; jj++) {
        int j = w * 16 + jj;
        // prefetch next jj's weight column (wraps to col0 on last iter —
        // branchless, redundant load is harmless)
        float4 rvn = rwP[col0 + (((jj + 1) & 15) << 6)];
        v2f R0 = {rv.x, rv.x}, R1 = {rv.y, rv.y}, R2 = {rv.z, rv.z}, RB = {rv.w, rv.w};
        const float4* g4 = (const float4*)(&s_gvt[j][0]);
#pragma unroll
        for (int q = 0; q < 6; q++) {
            float4 g = g4[q];
            v2f ga = {g.x, g.y};
            v2f gb = {g.z, g.w};
            v2f t0 = pk_fma(rx[2 * q], R0, pk_fma(ry[2 * q], R1, pk_fma(rz[2 * q], R2, RB)));
            v2f t1 = pk_fma(rx[2 * q + 1], R0, pk_fma(ry[2 * q + 1], R1, pk_fma(rz[2 * q + 1], R2, RB)));
            v2f e0 = {EXP2(t0.x), EXP2(t0.y)};
            v2f e1 = {EXP2(t1.x), EXP2(t1.y)};
            l0 = pk_add(l0, e0);
            l1 = pk_add(l1, e1);
            a0 = pk_fma(ga, e0, a0);
            a1 = pk_fma(gb, e1, a1);
        }
        rv = rvn;
    }
    s_red[w][d] = l0.x + l0.y + l1.x + l1.y;
    s_red[4 + w][d] = a0.x + a0.y + a1.x + a1.y;
    __syncthreads();
    if (tid < 64) {
        float L = s_red[0][d] + s_red[1][d] + s_red[2][d] + s_red[3][d];
        float A = s_red[4][d] + s_red[5][d] + s_red[6][d] + s_red[7][d];
        s_pre[d] = A / L;
    }
    __syncthreads();
    // out[pt][d] = sum_dd s_pre[dd] * sw[dd][d] + sb[d]
    float part = 0.f;
#pragma unroll
    for (int dd = 0; dd < 16; dd++) {
        int drow = w * 16 + dd;
        part = __builtin_fmaf(s_pre[drow], sw[drow * 64 + d], part);
    }
    s_red[w][d] = part;
    __syncthreads();
    if (tid < 64) {
        float o = s_red[0][d] + s_red[1][d] + s_red[2][d] + s_red[3][d] + sb[d];
        out[(size_t)pt * 64 + d] = o;
    }
    if (pt == 0 && tid == 0) out[(size_t)NPTS * 64] = 1024.0f;  // second output: N
}

extern "C" void kernel_launch(void* const* d_in, const int* in_sizes, int n_in,
                              void* d_out, int out_size, void* d_ws, size_t ws_size,
                              hipStream_t stream) {
    const float* feature = (const float*)d_in[0];
    const float* xyz = (const float*)d_in[1];
    const float* pw1 = (const float*)d_in[2];
    const float* pb1 = (const float*)d_in[3];
    const float* pw2 = (const float*)d_in[4];
    const float* pb2 = (const float*)d_in[5];
    const float* rw = (const float*)d_in[6];
    const float* rb = (const float*)d_in[7];
    const float* sw = (const float*)d_in[8];
    const float* sb = (const float*)d_in[9];
    float* out = (float*)d_out;

    char* ws = (char*)d_ws;
    float* feat = (float*)(ws);             // 512 KiB
    int* idx = (int*)(ws + 524288);         // 192 KiB
    float4* rwP = (float4*)(ws + 720896);   // 64 KiB

    prep_mlp_knn_kernel<<<1040, 256, 0, stream>>>(feature, xyz, pw1, pb1, pw2, pb2,
                                                  rw, rb, feat, idx, rwP);
    agg_kernel<<<NPTS, 256, 0, stream>>>(xyz, feat, idx, rwP, sw, sb, out);
}

// Round 8
// 137.878 us; speedup vs baseline: 1.0146x; 1.0146x over previous
//
#include <hip/hip_runtime.h>
#include <math.h>

// Problem constants (baked from reference setup_inputs):
// B=2, N=1024, Din=64, D=64, K=24
#define BB 2
#define NN 1024
#define DD 64
#define KK 24
#define NPTS (BB * NN)  // 2048

#if __has_builtin(__builtin_amdgcn_exp2f)
#define EXP2(x) __builtin_amdgcn_exp2f(x)
#else
#define EXP2(x) exp2f(x)
#endif

typedef float v2f __attribute__((ext_vector_type(2)));

// VOP3P packed f32 (LLVM does not form these from ext_vector ops).
// NOTE (R7 lesson): all VOP3P f32 sources must be 64-bit VGPR pairs —
// op_sel_hi single-reg broadcast does NOT assemble on gfx950. Broadcast
// scalars must be packed into v2f pairs explicitly.
static __device__ __forceinline__ v2f pk_fma(v2f a, v2f b, v2f c) {
    v2f d;
    asm("v_pk_fma_f32 %0, %1, %2, %3" : "=v"(d) : "v"(a), "v"(b), "v"(c));
    return d;
}
static __device__ __forceinline__ v2f pk_add(v2f a, v2f b) {
    v2f d;
    asm("v_pk_add_f32 %0, %1, %2" : "=v"(d) : "v"(a), "v"(b));
    return d;
}

// ---------------------------------------------------------------------------
// Workspace layout (bytes):
//   feat : [2048][64] float   @ 0        (512 KiB)
//   idx  : [2048][24] int     @ 524288   (192 KiB)
//   rwP  : [4096] float4      @ 720896   (64 KiB)  {rw0,rw1,rw2,rb}*log2(e)
// ---------------------------------------------------------------------------

// Fused prep + MLP + KNN, role-split by blockIdx:
//   blocks [0,512)    : MLP, 4 points per block
//   blocks [512,528)  : rw/rb prescale+interleave
//   blocks [528,1040) : KNN, 4 points per block (one wave per point)
__global__ __launch_bounds__(256) void prep_mlp_knn_kernel(
    const float* __restrict__ feature, const float* __restrict__ xyz,
    const float* __restrict__ pw1, const float* __restrict__ pb1,
    const float* __restrict__ pw2, const float* __restrict__ pb2,
    const float* __restrict__ rw, const float* __restrict__ rb,
    float* __restrict__ feat, int* __restrict__ idx_out,
    float4* __restrict__ rwP) {
    int bid = blockIdx.x;
    int tid = threadIdx.x;

    if (bid < 512) {
        // ---- MLP: feat = relu(relu(feature@pw1+pb1)@pw2+pb2), 4 rows/block
        int r = tid >> 6;
        int d = tid & 63;
        int row = bid * 4 + r;
        __shared__ float s_in[4][64];
        __shared__ float s_h[4][64];
        s_in[r][d] = feature[row * 64 + d];
        __syncthreads();
        float h = pb1[d];
#pragma unroll
        for (int i = 0; i < 64; i++) h = __builtin_fmaf(s_in[r][i], pw1[i * 64 + d], h);
        h = fmaxf(h, 0.f);
        s_h[r][d] = h;
        __syncthreads();
        float f = pb2[d];
#pragma unroll
        for (int i = 0; i < 64; i++) f = __builtin_fmaf(s_h[r][i], pw2[i * 64 + d], f);
        f = fmaxf(f, 0.f);
        feat[row * 64 + d] = f;
    } else if (bid < 528) {
        // ---- prescale rw/rb by log2(e), interleave to float4 per column
        const float LOG2E = 1.4426950408889634f;
        int t = (bid - 512) * 256 + tid;  // 0..4095
        float4 v;
        v.x = rw[t] * LOG2E;
        v.y = rw[4096 + t] * LOG2E;
        v.z = rw[8192 + t] * LOG2E;
        v.w = rb[t] * LOG2E;
        rwP[t] = v;
    } else {
        // ---- KNN: one wave per point, iterative argmin (24 rounds)
        int w = tid >> 6;
        int lane = tid & 63;
        int pt = (bid - 528) * 4 + w;
        int b = pt >> 10;
        int n = pt & 1023;
        const float* xb = xyz + (size_t)b * NN * 3;
        float xn = xb[n * 3 + 0], yn = xb[n * 3 + 1], zn = xb[n * 3 + 2];
        float sqn = xn * xn + yn * yn + zn * zn;
        float dist[16];
#pragma unroll
        for (int c = 0; c < 16; c++) {
            int m = c * 64 + lane;
            float xm = xb[m * 3 + 0], ym = xb[m * 3 + 1], zm = xb[m * 3 + 2];
            float sqm = xm * xm + ym * ym + zm * zm;
            float dot = xn * xm + yn * ym + zn * zm;
            dist[c] = sqn + sqm - 2.0f * dot;
        }
        for (int r = 0; r < KK; r++) {
            float best = 3.4e38f;
            int bi = 1 << 30;
#pragma unroll
            for (int c = 0; c < 16; c++) {
                if (dist[c] < best) {  // strict < keeps lowest index on ties
                    best = dist[c];
                    bi = c * 64 + lane;
                }
            }
#pragma unroll
            for (int off = 32; off >= 1; off >>= 1) {
                float ob = __shfl_down(best, off);
                int oi = __shfl_down(bi, off);
                if (ob < best || (ob == best && oi < bi)) {
                    best = ob;
                    bi = oi;
                }
            }
            bi = __shfl(bi, 0);
            if ((bi & 63) == lane) dist[bi >> 6] = 3.4e38f;
            if (lane == 0) idx_out[pt * KK + r] = bi;
        }
    }
}

// Fused weight-gen + softmax + aggregate + final linear.
// RESTRUCTURED: wave w owns k-slice [6w, 6w+6) and sweeps ALL j=0..63.
// Why: R1-R6 the compiler LDS-sunk the 72-VGPR j-sliced rel set; the hot
// loop carried ~40 broadcast ds_reads per jj and the per-CU LDS pipe
// saturated. With k-slices, rel is only 18 floats/wave (computed from
// global xyz, never touches LDS) and gv costs 3 ds_read_b128 per j-PAIR
// (k-pair-interleaved layout).
__global__ __launch_bounds__(256, 4) void agg_kernel(const float* __restrict__ xyz,
                                                     const float* __restrict__ feat,
                                                     const int* __restrict__ idx,
                                                     const float4* __restrict__ rwP,
                                                     const float* __restrict__ sw,
                                                     const float* __restrict__ sb,
                                                     float* __restrict__ out) {
    int pt = blockIdx.x;
    int b = pt >> 10;
    int n = pt & 1023;
    int tid = threadIdx.x;
    int w = tid >> 6;
    int d = tid & 63;

    __shared__ __align__(16) float s_gvp[12][64][2];  // [k/2][j][k&1]
    __shared__ float s_red[8][64];
    __shared__ float s_pre[64];

    const float* xb = xyz + (size_t)b * NN * 3;

    // stage gv: s_gvp[k>>1][j][k&1] = feat[nb_k][j]  (writes j-contiguous,
    // stride-2 dwords -> 4-way conflict on 6 instrs, negligible)
    for (int t = tid; t < KK * 64; t += 256) {
        int k = t >> 6, j = t & 63;
        int nb = idx[pt * KK + k];
        s_gvp[k >> 1][j][k & 1] = feat[((size_t)b * NN + nb) * 64 + j];
    }

    // rel for this wave's 6 k's — straight from global (uniform, L1-hit),
    // 18 floats in VGPRs. No LDS involvement.
    float cx = xb[n * 3 + 0], cy = xb[n * 3 + 1], cz = xb[n * 3 + 2];
    v2f rxp[3], ryp[3], rzp[3];
#pragma unroll
    for (int p = 0; p < 3; p++) {
        int nb0 = idx[pt * KK + w * 6 + 2 * p];
        int nb1 = idx[pt * KK + w * 6 + 2 * p + 1];
        rxp[p] = (v2f){xb[nb0 * 3 + 0] - cx, xb[nb1 * 3 + 0] - cx};
        ryp[p] = (v2f){xb[nb0 * 3 + 1] - cy, xb[nb1 * 3 + 1] - cy};
        rzp[p] = (v2f){xb[nb0 * 3 + 2] - cz, xb[nb1 * 3 + 2] - cz};
    }
    __syncthreads();

    v2f l0 = {0.f, 0.f}, l1 = {0.f, 0.f}, l2 = {0.f, 0.f};
    v2f a0 = {0.f, 0.f}, a1 = {0.f, 0.f}, a2 = {0.f, 0.f};
    int kp0 = 3 * w;

    // prefetched state for j-pair {2jg, 2jg+1}
    float4 G0 = *(const float4*)&s_gvp[kp0 + 0][0][0];
    float4 G1 = *(const float4*)&s_gvp[kp0 + 1][0][0];
    float4 G2 = *(const float4*)&s_gvp[kp0 + 2][0][0];
    float4 rv0 = rwP[d];
    float4 rv1 = rwP[64 + d];

    for (int jg = 0; jg < 32; jg++) {
        int jn = ((jg + 1) & 31) * 2;  // branchless wrap on last iter
        float4 G0n = *(const float4*)&s_gvp[kp0 + 0][jn][0];
        float4 G1n = *(const float4*)&s_gvp[kp0 + 1][jn][0];
        float4 G2n = *(const float4*)&s_gvp[kp0 + 2][jn][0];
        float4 rv0n = rwP[jn * 64 + d];
        float4 rv1n = rwP[(jn + 1) * 64 + d];

        // ---- j = 2*jg  (weights rv0, gv = G*.xy)
        {
            v2f B0 = {rv0.x, rv0.x}, B1 = {rv0.y, rv0.y}, B2 = {rv0.z, rv0.z}, BBv = {rv0.w, rv0.w};
            v2f t0 = pk_fma(rxp[0], B0, pk_fma(ryp[0], B1, pk_fma(rzp[0], B2, BBv)));
            v2f t1 = pk_fma(rxp[1], B0, pk_fma(ryp[1], B1, pk_fma(rzp[1], B2, BBv)));
            v2f t2 = pk_fma(rxp[2], B0, pk_fma(ryp[2], B1, pk_fma(rzp[2], B2, BBv)));
            v2f e0 = {EXP2(t0.x), EXP2(t0.y)};
            v2f e1 = {EXP2(t1.x), EXP2(t1.y)};
            v2f e2 = {EXP2(t2.x), EXP2(t2.y)};
            l0 = pk_add(l0, e0);
            l1 = pk_add(l1, e1);
            l2 = pk_add(l2, e2);
            a0 = pk_fma((v2f){G0.x, G0.y}, e0, a0);
            a1 = pk_fma((v2f){G1.x, G1.y}, e1, a1);
            a2 = pk_fma((v2f){G2.x, G2.y}, e2, a2);
        }
        // ---- j = 2*jg+1  (weights rv1, gv = G*.zw)
        {
            v2f B0 = {rv1.x, rv1.x}, B1 = {rv1.y, rv1.y}, B2 = {rv1.z, rv1.z}, BBv = {rv1.w, rv1.w};
            v2f t0 = pk_fma(rxp[0], B0, pk_fma(ryp[0], B1, pk_fma(rzp[0], B2, BBv)));
            v2f t1 = pk_fma(rxp[1], B0, pk_fma(ryp[1], B1, pk_fma(rzp[1], B2, BBv)));
            v2f t2 = pk_fma(rxp[2], B0, pk_fma(ryp[2], B1, pk_fma(rzp[2], B2, BBv)));
            v2f e0 = {EXP2(t0.x), EXP2(t0.y)};
            v2f e1 = {EXP2(t1.x), EXP2(t1.y)};
            v2f e2 = {EXP2(t2.x), EXP2(t2.y)};
            l0 = pk_add(l0, e0);
            l1 = pk_add(l1, e1);
            l2 = pk_add(l2, e2);
            a0 = pk_fma((v2f){G0.z, G0.w}, e0, a0);
            a1 = pk_fma((v2f){G1.z, G1.w}, e1, a1);
            a2 = pk_fma((v2f){G2.z, G2.w}, e2, a2);
        }
        G0 = G0n; G1 = G1n; G2 = G2n;
        rv0 = rv0n; rv1 = rv1n;
    }

    s_red[w][d] = (l0.x + l0.y) + (l1.x + l1.y) + (l2.x + l2.y);
    s_red[4 + w][d] = (a0.x + a0.y) + (a1.x + a1.y) + (a2.x + a2.y);
    __syncthreads();
    if (tid < 64) {
        float L = s_red[0][d] + s_red[1][d] + s_red[2][d] + s_red[3][d];
        float A = s_red[4][d] + s_red[5][d] + s_red[6][d] + s_red[7][d];
        s_pre[d] = A / L;
    }
    __syncthreads();
    // out[pt][d] = sum_dd s_pre[dd] * sw[dd][d] + sb[d]
    float part = 0.f;
#pragma unroll
    for (int dd = 0; dd < 16; dd++) {
        int drow = w * 16 + dd;
        part = __builtin_fmaf(s_pre[drow], sw[drow * 64 + d], part);
    }
    s_red[w][d] = part;
    __syncthreads();
    if (tid < 64) {
        float o = s_red[0][d] + s_red[1][d] + s_red[2][d] + s_red[3][d] + sb[d];
        out[(size_t)pt * 64 + d] = o;
    }
    if (pt == 0 && tid == 0) out[(size_t)NPTS * 64] = 1024.0f;  // second output: N
}

extern "C" void kernel_launch(void* const* d_in, const int* in_sizes, int n_in,
                              void* d_out, int out_size, void* d_ws, size_t ws_size,
                              hipStream_t stream) {
    const float* feature = (const float*)d_in[0];
    const float* xyz = (const float*)d_in[1];
    const float* pw1 = (const float*)d_in[2];
    const float* pb1 = (const float*)d_in[3];
    const float* pw2 = (const float*)d_in[4];
    const float* pb2 = (const float*)d_in[5];
    const float* rw = (const float*)d_in[6];
    const float* rb = (const float*)d_in[7];
    const float* sw = (const float*)d_in[8];
    const float* sb = (const float*)d_in[9];
    float* out = (float*)d_out;

    char* ws = (char*)d_ws;
    float* feat = (float*)(ws);             // 512 KiB
    int* idx = (int*)(ws + 524288);         // 192 KiB
    float4* rwP = (float4*)(ws + 720896);   // 64 KiB

    prep_mlp_knn_kernel<<<1040, 256, 0, stream>>>(feature, xyz, pw1, pb1, pw2, pb2,
                                                  rw, rb, feat, idx, rwP);
    agg_kernel<<<NPTS, 256, 0, stream>>>(xyz, feat, idx, rwP, sw, sb, out);
}